// Round 4
// baseline (653.747 us; speedup 1.0000x reference)
//
#include <hip/hip_runtime.h>
#include <cstdint>
#include <cstddef>

#define NB 16
#define T_ 2048
#define D_ 512
#define F_ 2048

using f16 = _Float16;
typedef __attribute__((ext_vector_type(8))) f16 f16x8;
typedef __attribute__((ext_vector_type(4))) f16 f16x4;
typedef __attribute__((ext_vector_type(4))) float f32x4;

// ---------------- async global->LDS (16B per lane, wave-uniform LDS base) ----
__device__ __forceinline__ void g2l16(const f16* g, f16* l) {
  __builtin_amdgcn_global_load_lds((const __attribute__((address_space(1))) void*)g,
                                   (__attribute__((address_space(3))) void*)l,
                                   16, 0, 0);
}

// ---------------- 256x256 GEMM, BK=64, mixed-depth counted pipeline ---------
// A tile 256x64 f16 (32KB): TRIPLE-buffered, staged 2 K-tiles ahead (covers
// HBM ~900cy). B tile 256x64: DOUBLE-buffered, staged 1 ahead (weights are
// L2-resident). LDS = 3*32 + 2*32 = 160KB. 512 thr, 8 waves (2M x 4N), wave
// tile 128x64: 24 ds_read_b128 : 64 MFMA per K-tile. Issue order per iter t:
// [A(t+2) 4loads, B(t+1) 4loads] -> steady vmcnt(8) guarantees A(t),B(t)
// landed with 8 newest (A(t+2),B(t+1)) still in flight. Tail: vmcnt(4)/0.
// Rows are 128B = 8 16B-slots, slot ^= row&7 (conflict-free b128 reads,
// verified 0 conflicts in R3); global source pre-swizzled (rule #21).
template<int EPI>
__global__ __launch_bounds__(512, 2) void gemm_kernel(
    const f16* __restrict__ A, int lda,
    const f16* __restrict__ Bt, int ldb,
    void* __restrict__ Cv, int ldc,
    const float* __restrict__ bias, int K, int nN)
{
  __shared__ __align__(16) char smem[163840];   // A bufs @0,32K,64K ; B @96K,128K

  const int nwg = gridDim.x, wg = blockIdx.x;
  const int cpx = nwg >> 3;
  const int swz = (wg & 7)*cpx + (wg >> 3);     // bijective: grids are %8==0
  const int n0 = (swz % nN) * 256;
  const int m0 = (swz / nN) * 256;

  const int tid = threadIdx.x;
  const int wid = tid >> 6, lane = tid & 63;
  const int wm = wid >> 2, wn = wid & 3;
  const int lr = lane & 15, ks = lane >> 4;

  // staging geometry: 32KB tile = 512 thr x 4 issues x 16B
  int ldso[4]; size_t gA[4], gB[4];
  #pragma unroll
  for (int i = 0; i < 4; ++i) {
    int o = i*8192 + tid*16;
    int row = o >> 7;
    int ss = ((o >> 4) & 7) ^ (row & 7);        // pre-swizzled source slot
    ldso[i] = o;
    gA[i] = (size_t)row*lda + ss*8;
    gB[i] = (size_t)row*ldb + ss*8;
  }
  const f16* Ab = A  + (size_t)m0*lda;
  const f16* Bb = Bt + (size_t)n0*ldb;

  auto stageA = [&](int t) {
    const f16* src = Ab + t*64;
    char* dst = smem + (t % 3)*32768;
    #pragma unroll
    for (int i = 0; i < 4; ++i) g2l16(src + gA[i], (f16*)(dst + ldso[i]));
  };
  auto stageB = [&](int t) {
    const f16* src = Bb + t*64;
    char* dst = smem + 98304 + (t & 1)*32768;
    #pragma unroll
    for (int i = 0; i < 4; ++i) g2l16(src + gB[i], (f16*)(dst + ldso[i]));
  };

  // fragment LDS byte offsets
  int offA[8][2], offB[4][2];
  #pragma unroll
  for (int mi = 0; mi < 8; ++mi) {
    int row = wm*128 + mi*16 + lr;
    #pragma unroll
    for (int k = 0; k < 2; ++k)
      offA[mi][k] = row*128 + (((k*4 + ks) ^ (row & 7)) << 4);
  }
  #pragma unroll
  for (int ni = 0; ni < 4; ++ni) {
    int row = wn*64 + ni*16 + lr;
    #pragma unroll
    for (int k = 0; k < 2; ++k)
      offB[ni][k] = row*128 + (((k*4 + ks) ^ (row & 7)) << 4);
  }

  f32x4 acc[8][4];
  #pragma unroll
  for (int i = 0; i < 8; ++i)
    #pragma unroll
    for (int j = 0; j < 4; ++j) acc[i][j] = f32x4{0.f, 0.f, 0.f, 0.f};

  const int nk = K >> 6;
  stageA(0); stageA(1); stageB(0);              // 12 loads

  for (int t = 0; t < nk; ++t) {
    if (t + 2 < nk) stageA(t + 2);
    if (t + 1 < nk) stageB(t + 1);
    if (t + 2 < nk)      { asm volatile("s_waitcnt vmcnt(8)" ::: "memory"); }
    else if (t + 1 < nk) { asm volatile("s_waitcnt vmcnt(4)" ::: "memory"); }
    else                 { asm volatile("s_waitcnt vmcnt(0)" ::: "memory"); }
    __builtin_amdgcn_s_barrier();

    const char* pA = (const char*)smem + (t % 3)*32768;
    const char* pB = (const char*)smem + 98304 + (t & 1)*32768;

    f16x8 bf[4][2], af1[4][2], af2[4][2];
    #pragma unroll
    for (int ni = 0; ni < 4; ++ni)
      #pragma unroll
      for (int k = 0; k < 2; ++k) bf[ni][k] = *(const f16x8*)(pB + offB[ni][k]);
    #pragma unroll
    for (int mi = 0; mi < 4; ++mi)
      #pragma unroll
      for (int k = 0; k < 2; ++k) af1[mi][k] = *(const f16x8*)(pA + offA[mi][k]);
    asm volatile("s_waitcnt lgkmcnt(0)" ::: "memory");
    __builtin_amdgcn_sched_barrier(0);
    #pragma unroll
    for (int k = 0; k < 2; ++k)
      #pragma unroll
      for (int mi = 0; mi < 4; ++mi)
        #pragma unroll
        for (int ni = 0; ni < 4; ++ni)
          acc[mi][ni] = __builtin_amdgcn_mfma_f32_16x16x32_f16(af1[mi][k], bf[ni][k], acc[mi][ni], 0, 0, 0);
    #pragma unroll
    for (int mi = 0; mi < 4; ++mi)
      #pragma unroll
      for (int k = 0; k < 2; ++k) af2[mi][k] = *(const f16x8*)(pA + offA[mi + 4][k]);
    asm volatile("s_waitcnt lgkmcnt(0)" ::: "memory");
    __builtin_amdgcn_sched_barrier(0);
    #pragma unroll
    for (int k = 0; k < 2; ++k)
      #pragma unroll
      for (int mi = 0; mi < 4; ++mi)
        #pragma unroll
        for (int ni = 0; ni < 4; ++ni)
          acc[mi + 4][ni] = __builtin_amdgcn_mfma_f32_16x16x32_f16(af2[mi][k], bf[ni][k], acc[mi + 4][ni], 0, 0, 0);
    __builtin_amdgcn_sched_barrier(0);
    __builtin_amdgcn_s_barrier();               // reads done before restage
  }

  const int lq = lane >> 4;
  #pragma unroll
  for (int mi = 0; mi < 8; ++mi) {
    #pragma unroll
    for (int ni = 0; ni < 4; ++ni) {
      int col = n0 + wn*64 + ni*16 + lr;
      float bv = bias[col];
      int rbase = m0 + wm*128 + mi*16 + lq*4;
      #pragma unroll
      for (int r = 0; r < 4; ++r) {
        float val = acc[mi][ni][r] + bv;
        size_t o = (size_t)(rbase + r)*ldc + col;
        if (EPI == 0) {
          ((f16*)Cv)[o] = (f16)val;
        } else if (EPI == 1) {
          val = 0.5f * val * (1.f + erff(val * 0.70710678118654752f));
          ((f16*)Cv)[o] = (f16)val;
        } else {
          float* Cf = (float*)Cv;
          Cf[o] = Cf[o] + val;
        }
      }
    }
  }
}

// ---------------- score v3: diagonal-accumulated, D-quartered, 2 blocks/CU --
__device__ __forceinline__ void diag_epilogue2(float* ctile, f32x4 (&acc)[4][4],
                                               int dg, int b, float* __restrict__ score)
{
  const int tid = threadIdx.x;
  const int w = tid >> 6, lane = tid & 63;
  const int wm = w >> 1, wn = w & 1, lr = lane & 15, lq = lane >> 4;
  float total = 0.f;
  #pragma unroll
  for (int pass = 0; pass < 2; ++pass) {
    __builtin_amdgcn_s_barrier();                 // ctile free
    if (wn == pass) {
      #pragma unroll
      for (int mi = 0; mi < 4; ++mi) {
        #pragma unroll
        for (int ni = 0; ni < 4; ++ni) {
          int colL = ni*16 + lr;
          int row0 = wm*64 + mi*16 + lq*4;
          *(f32x4*)(&ctile[colL*128 + row0]) = acc[mi][ni];
        }
      }
    }
    asm volatile("s_waitcnt lgkmcnt(0)" ::: "memory");
    __builtin_amdgcn_s_barrier();
    if (tid < 255) {
      int delta = tid - 127;
      #pragma unroll 8
      for (int cc = 0; cc < 64; ++cc) {
        int r = pass*64 + cc + delta;
        if ((unsigned)r < 128u) total += ctile[cc*128 + r];
      }
    }
    asm volatile("s_waitcnt lgkmcnt(0)" ::: "memory");
  }
  __builtin_amdgcn_s_barrier();
  if (tid < 255) {
    int tau = dg*128 + (tid - 127);
    if (tau >= 1 && tau < T_) atomicAdd(&score[(size_t)b*T_ + tau], total);
  }
}

__global__ __launch_bounds__(256, 2) void score2_kernel(
    const f16* __restrict__ qkv, float* __restrict__ score)
{
  __shared__ __align__(16) f16 stage[3*8192];
  __shared__ float ctile[64*128];

  const int b = blockIdx.x, h = blockIdx.y, g = blockIdx.z;
  const int tid = threadIdx.x;
  const int w = tid >> 6, lane = tid & 63;

  const int o0 = (w*2+0)*1024 + lane*16;
  const int o1 = (w*2+1)*1024 + lane*16;
  const int r0 = o0 >> 6, r1 = o1 >> 6;
  const int s0 = ((o0>>4)&3) ^ ((r0>>1)&3);
  const int s1 = ((o1>>4)&3) ^ ((r1>>1)&3);
  const size_t goff0 = (size_t)r0*1536 + s0*8;
  const size_t goff1 = (size_t)r1*1536 + s1*8;
  const int l0 = (w*2+0)*512, l1 = (w*2+1)*512;

  const int nA = 16 - g;
  const int nsteps = 17*4;
  const int groupA_end = nA*4;

  const int wm = w >> 1, wn = w & 1;
  const int lr = lane & 15, ks = lane >> 4;
  int offQ[4], offK[4];
  #pragma unroll
  for (int i = 0; i < 4; ++i) {
    int row = wm*64 + i*16 + lr;
    offQ[i] = row*64 + ((ks ^ ((row>>1)&3)) << 4);
    int col = wn*64 + i*16 + lr;
    offK[i] = col*64 + ((ks ^ ((col>>1)&3)) << 4);
  }

  auto issue = [&](int sp) {
    int p = sp >> 2, kt = sp & 3;
    int ti, tj;
    if (p < nA) { tj = p; ti = p + g; }
    else        { tj = p - nA; ti = tj + 15 - g; }
    size_t qb = ((size_t)(b*T_ + ti*128))*1536 + h*128 + kt*32;
    size_t kb = ((size_t)(b*T_ + tj*128))*1536 + 512 + h*128 + kt*32;
    f16* dst = stage + (sp % 3)*8192;
    g2l16(qkv + qb + goff0, dst + l0);
    g2l16(qkv + qb + goff1, dst + l1);
    g2l16(qkv + kb + goff0, dst + 4096 + l0);
    g2l16(qkv + kb + goff1, dst + 4096 + l1);
  };

  f32x4 acc[4][4];
  #pragma unroll
  for (int i = 0; i < 4; ++i)
    #pragma unroll
    for (int j = 0; j < 4; ++j) acc[i][j] = f32x4{0.f, 0.f, 0.f, 0.f};

  issue(0);
  issue(1);
  asm volatile("s_waitcnt vmcnt(4)" ::: "memory");
  __builtin_amdgcn_s_barrier();

  for (int sp = 0; sp < nsteps; ++sp) {
    const char* base = (const char*)stage + (sp % 3)*16384;
    f16x8 af[4], bf[4];
    #pragma unroll
    for (int i = 0; i < 4; ++i) {
      af[i] = *(const f16x8*)(base + offQ[i]);
      bf[i] = *(const f16x8*)(base + 8192 + offK[i]);
    }
    if (sp + 2 < nsteps) issue(sp + 2);
    asm volatile("s_waitcnt lgkmcnt(0)" ::: "memory");
    __builtin_amdgcn_sched_barrier(0);
    #pragma unroll
    for (int mi = 0; mi < 4; ++mi)
      #pragma unroll
      for (int ni = 0; ni < 4; ++ni)
        acc[mi][ni] = __builtin_amdgcn_mfma_f32_16x16x32_f16(af[mi], bf[ni], acc[mi][ni], 0, 0, 0);
    if (sp + 2 < nsteps) { asm volatile("s_waitcnt vmcnt(4)" ::: "memory"); }
    else                 { asm volatile("s_waitcnt vmcnt(0)" ::: "memory"); }
    __builtin_amdgcn_s_barrier();
    if (sp == groupA_end - 1) {
      diag_epilogue2(ctile, acc, g, b, score);
      #pragma unroll
      for (int i = 0; i < 4; ++i)
        #pragma unroll
        for (int j = 0; j < 4; ++j) acc[i][j] = f32x4{0.f, 0.f, 0.f, 0.f};
    }
  }
  diag_epilogue2(ctile, acc, 15 - g, b, score);
}

__global__ void topk_kernel(const float* __restrict__ score, int* __restrict__ lags)
{
  const int b = blockIdx.x, tid = threadIdx.x;
  __shared__ float vals[T_];
  __shared__ float rmax[256];
  __shared__ int   rarg[256];
  __shared__ int   outk[8];
  for (int t = tid; t < T_; t += 256) vals[t] = (t == 0) ? -1e30f : score[(size_t)b*T_ + t];
  __syncthreads();
  for (int k = 0; k < 8; ++k) {
    float m = -1e30f; int mi = 0x7fffffff;
    for (int t = tid; t < T_; t += 256) {
      float v = vals[t];
      if (v > m || (v == m && t < mi)) { m = v; mi = t; }
    }
    rmax[tid] = m; rarg[tid] = mi;
    __syncthreads();
    for (int s = 128; s > 0; s >>= 1) {
      if (tid < s) {
        float v2 = rmax[tid+s]; int i2 = rarg[tid+s];
        if (v2 > rmax[tid] || (v2 == rmax[tid] && i2 < rarg[tid])) { rmax[tid] = v2; rarg[tid] = i2; }
      }
      __syncthreads();
    }
    if (tid == 0) { outk[k] = rarg[0]; vals[rarg[0]] = -1e30f; }
    __syncthreads();
  }
  if (tid < 8) lags[b*8 + tid] = outk[tid];
}

// trend1 = movavg25(x) -> out_trend ; s1 = x - trend1 -> f16
__global__ void decomp1_kernel(const float* __restrict__ x,
                               float* __restrict__ trend1, f16* __restrict__ s16)
{
  int idx = blockIdx.x*256 + threadIdx.x;              // (b, t, d4)
  int d4 = idx & 127, t = (idx >> 7) & (T_-1), b = idx >> 18;
  const float* xb = x + ((size_t)b*T_)*D_ + d4*4;
  f32x4 sum = {0.f,0.f,0.f,0.f};
  f32x4 center = {0.f,0.f,0.f,0.f};
  #pragma unroll
  for (int j = -12; j <= 12; ++j) {
    int tt = t + j; tt = tt < 0 ? 0 : (tt > T_-1 ? T_-1 : tt);
    f32x4 v = *(const f32x4*)(xb + (size_t)tt*D_);
    sum += v;
    if (j == 0) center = v;
  }
  f32x4 tr = sum * (1.f/25.f);
  size_t o = ((size_t)(b*T_ + t))*D_ + d4*4;
  *(f32x4*)(trend1 + o) = tr;
  f32x4 s = center - tr;
  f16x4 hv;
  #pragma unroll
  for (int i = 0; i < 4; ++i) hv[i] = (f16)s[i];
  *(f16x4*)(s16 + o) = hv;
}

// sac16 (act0, f16): trend2 = movavg25 ; s2 = sac - trend2 -> seas(f32) + s2_16 ;
// trend_io += trend2
__global__ void decomp2_kernel(const f16* __restrict__ sac,
                               float* __restrict__ seas, float* __restrict__ trend_io,
                               f16* __restrict__ s2_16)
{
  int idx = blockIdx.x*256 + threadIdx.x;
  int d4 = idx & 127, t = (idx >> 7) & (T_-1), b = idx >> 18;
  const f16* sb = sac + ((size_t)b*T_)*D_ + d4*4;
  f32x4 sum = {0.f,0.f,0.f,0.f};
  f32x4 center = {0.f,0.f,0.f,0.f};
  #pragma unroll
  for (int j = -12; j <= 12; ++j) {
    int tt = t + j; tt = tt < 0 ? 0 : (tt > T_-1 ? T_-1 : tt);
    f16x4 v = *(const f16x4*)(sb + (size_t)tt*D_);
    f32x4 vf = { (float)v[0], (float)v[1], (float)v[2], (float)v[3] };
    sum += vf;
    if (j == 0) center = vf;
  }
  f32x4 tr = sum * (1.f/25.f);
  size_t o = ((size_t)(b*T_ + t))*D_ + d4*4;
  f32x4 s = center - tr;
  *(f32x4*)(seas + o) = s;
  f16x4 hv;
  #pragma unroll
  for (int i = 0; i < 4; ++i) hv[i] = (f16)s[i];
  *(f16x4*)(s2_16 + o) = hv;
  f32x4 told = *(const f32x4*)(trend_io + o);
  *(f32x4*)(trend_io + o) = told + tr;
}

// act0 := s1_16 + (1/8) sum_k v[(t - lag_k) mod T]   (in-place, element-wise)
__global__ void gather_kernel(const f16* __restrict__ qkv, f16* __restrict__ act,
                              const int* __restrict__ lags)
{
  int idx = blockIdx.x*256 + threadIdx.x;              // (b, t, d8)
  int d8 = idx & 63, t = (idx >> 6) & (T_-1), b = idx >> 17;
  const f16* vb = qkv + (size_t)b*T_*1536 + 1024 + d8*8;
  f16* ap = act + ((size_t)(b*T_ + t))*D_ + d8*8;
  f16x8 s = *(const f16x8*)ap;
  float a[8];
  #pragma unroll
  for (int j = 0; j < 8; ++j) a[j] = (float)s[j];
  #pragma unroll
  for (int k = 0; k < 8; ++k) {
    int lag = lags[b*8 + k];
    int tt = (t - lag + T_) & (T_-1);
    f16x8 v = *(const f16x8*)(vb + (size_t)tt*1536);
    #pragma unroll
    for (int j = 0; j < 8; ++j) a[j] += 0.125f * (float)v[j];
  }
  f16x8 o;
  #pragma unroll
  for (int j = 0; j < 8; ++j) o[j] = (f16)a[j];
  *(f16x8*)ap = o;
}

// convert weights to f16, transposed to (N x K) row-major; concat qkv biases
__global__ void prepack_kernel(const float* __restrict__ Wq, const float* __restrict__ Wk,
                               const float* __restrict__ Wv, const float* __restrict__ bq,
                               const float* __restrict__ bk, const float* __restrict__ bv,
                               const float* __restrict__ W1, const float* __restrict__ W2,
                               f16* __restrict__ wcat, f16* __restrict__ w1t,
                               f16* __restrict__ w2t, float* __restrict__ bcat)
{
  int i = blockIdx.x*256 + threadIdx.x;
  if (i < 786432) {                       // wcat: 1536 x 512
    int n = i >> 9, k = i & 511;
    int sel = n >> 9, nn = n & 511;
    const float* W = sel == 0 ? Wq : (sel == 1 ? Wk : Wv);
    wcat[i] = (f16)W[k*512 + nn];
  } else if (i < 1835008) {               // w1t: 2048 x 512
    int j = i - 786432;
    int n = j >> 9, k = j & 511;
    w1t[j] = (f16)W1[k*2048 + n];
  } else if (i < 2883584) {               // w2t: 512 x 2048
    int j = i - 1835008;
    int n = j >> 11, k = j & 2047;
    w2t[j] = (f16)W2[k*512 + n];
  } else if (i < 2885120) {               // bcat: 1536
    int j = i - 2883584;
    bcat[j] = j < 512 ? bq[j] : (j < 1024 ? bk[j-512] : bv[j-1024]);
  }
}

extern "C" void kernel_launch(void* const* d_in, const int* in_sizes, int n_in,
                              void* d_out, int out_size, void* d_ws, size_t ws_size,
                              hipStream_t stream)
{
  const float* x  = (const float*)d_in[0];
  const float* Wq = (const float*)d_in[1];
  const float* bq = (const float*)d_in[2];
  const float* Wk = (const float*)d_in[3];
  const float* bk = (const float*)d_in[4];
  const float* Wv = (const float*)d_in[5];
  const float* bv = (const float*)d_in[6];
  const float* W1 = (const float*)d_in[7];
  const float* b1 = (const float*)d_in[8];
  const float* W2 = (const float*)d_in[9];
  const float* b2 = (const float*)d_in[10];

  float* out_seas  = (float*)d_out;
  float* out_trend = out_seas + (size_t)NB*T_*D_;

  char* ws = (char*)d_ws;
  f16*   act0  = (f16*)(ws);                        //  [0, 32MiB): s1 -> sac (in place)
  f16*   qkv   = (f16*)(ws + 33554432ull);          //  [32, 128MiB): [q|k|v]
  f16*   s2_16 = qkv;                               //  [32, 64MiB) after qkv dead
  f16*   h16   = (f16*)(ws + 67108864ull);          //  [64, 192MiB): FFN hidden full-M
  f16*   wcat  = (f16*)(ws + 201326592ull);
  f16*   w1t   = (f16*)(ws + 202899456ull);
  f16*   w2t   = (f16*)(ws + 204996608ull);
  float* bcat  = (float*)(ws + 207093760ull);
  float* score = (float*)(ws + 207099904ull);
  int*   lags  = (int*)(ws + 207230976ull);

  (void)hipMemsetAsync(score, 0, (size_t)NB*T_*sizeof(float), stream);
  prepack_kernel<<<11270, 256, 0, stream>>>(Wq, Wk, Wv, bq, bk, bv, W1, W2,
                                            wcat, w1t, w2t, bcat);
  decomp1_kernel<<<NB*T_*(D_/4)/256, 256, 0, stream>>>(x, out_trend, act0);
  // QKV: (32768 x 512) @ (512 x 1536) -> qkv f16   [128 m x 6 n = 768 blocks]
  gemm_kernel<0><<<768, 512, 0, stream>>>(act0, 512, wcat, 512, qkv, 1536, bcat, 512, 6);
  score2_kernel<<<dim3(16, 4, 8), 256, 0, stream>>>(qkv, score);
  topk_kernel<<<NB, 256, 0, stream>>>(score, lags);
  gather_kernel<<<NB*T_*(D_/8)/256, 256, 0, stream>>>(qkv, act0, lags);
  decomp2_kernel<<<NB*T_*(D_/4)/256, 256, 0, stream>>>(act0, out_seas, out_trend, s2_16);
  // FFN full-M: (32768x512)@(512x2048) -> h16 ; (32768x2048)@(2048x512) += seas
  gemm_kernel<1><<<128*8, 512, 0, stream>>>(s2_16, 512, w1t, 512, h16, 2048, b1, 512, 8);
  gemm_kernel<2><<<128*2, 512, 0, stream>>>(h16, 2048, w2t, 2048, out_seas, 512, b2, 2048, 2);
}

// Round 5
// 646.340 us; speedup vs baseline: 1.0115x; 1.0115x over previous
//
#include <hip/hip_runtime.h>
#include <cstdint>
#include <cstddef>

#define NB 16
#define T_ 2048
#define D_ 512
#define F_ 2048

using f16 = _Float16;
typedef __attribute__((ext_vector_type(8))) f16 f16x8;
typedef __attribute__((ext_vector_type(4))) f16 f16x4;
typedef __attribute__((ext_vector_type(4))) float f32x4;

// ---------------- async global->LDS (16B per lane, wave-uniform LDS base) ----
__device__ __forceinline__ void g2l16(const f16* g, f16* l) {
  __builtin_amdgcn_global_load_lds((const __attribute__((address_space(1))) void*)g,
                                   (__attribute__((address_space(3))) void*)l,
                                   16, 0, 0);
}

// ---------------- 256x128 GEMM, BK=64, TRIPLE-buffered depth-2 pipeline -----
// 3 bufs x (A 256x64 = 32KB + B 128x64 = 16KB) = 144KB LDS, 1 block/CU.
// Stage full K-tile t+2 at iter t into buf (t+2)%3: that buf's previous
// tenant (t-1) was fully read before iter t began -> issue-safe by
// construction. Per-wave VMEM queue: A(x)=4 instrs, B(x)=2. Steady wait
// vmcnt(10) = keep [A(t+1),B(t+1),A(t+2)] in flight, tile t landed. Loads
// get ~2 iterations of latency cover (HBM ~900cy << cover).
// 8 waves 4Mx2N, wave tile 64x64. K-tile split into 2 phases (ks-half):
// each phase {8 ds_read_b128, lgkmcnt(0), setprio(1), 16 MFMA, setprio(0),
// barrier} -> wave role-split so setprio has something to arbitrate (T5).
// Rows 128B = 8 slots, slot ^= row&7: 0 bank conflicts (verified R3/R4).
template<int EPI>
__global__ __launch_bounds__(512, 2) void gemm_kernel(
    const f16* __restrict__ A, int lda,
    const f16* __restrict__ Bt, int ldb,
    void* __restrict__ Cv, int ldc,
    const float* __restrict__ bias, int K, int nN)
{
  __shared__ __align__(16) char smem[147456];

  const int nwg = gridDim.x, wg = blockIdx.x;
  const int cpx = nwg >> 3;
  const int swz = (wg & 7)*cpx + (wg >> 3);     // bijective: grids are %8==0
  const int n0 = (swz % nN) * 128;
  const int m0 = (swz / nN) * 256;

  const int tid = threadIdx.x;
  const int wid = tid >> 6, lane = tid & 63;
  const int wm = wid >> 1, wn = wid & 1;
  const int lr = lane & 15, ks = lane >> 4;

  // staging geometry (pre-swizzled global source, linear LDS dest)
  int ldsoA[4]; size_t gA[4];
  #pragma unroll
  for (int i = 0; i < 4; ++i) {
    int o = i*8192 + tid*16;
    int row = o >> 7;
    int ss = ((o >> 4) & 7) ^ (row & 7);
    ldsoA[i] = o;
    gA[i] = (size_t)row*lda + ss*8;
  }
  int ldsoB[2]; size_t gB[2];
  #pragma unroll
  for (int i = 0; i < 2; ++i) {
    int o = i*8192 + tid*16;
    int row = o >> 7;
    int ss = ((o >> 4) & 7) ^ (row & 7);
    ldsoB[i] = o;
    gB[i] = (size_t)row*ldb + ss*8;
  }
  const f16* Ab = A  + (size_t)m0*lda;
  const f16* Bb = Bt + (size_t)n0*ldb;

  auto stageA = [&](int t) {
    const f16* src = Ab + t*64;
    char* dst = smem + (t % 3)*49152;
    #pragma unroll
    for (int i = 0; i < 4; ++i) g2l16(src + gA[i], (f16*)(dst + ldsoA[i]));
  };
  auto stageB = [&](int t) {
    const f16* src = Bb + t*64;
    char* dst = smem + (t % 3)*49152 + 32768;
    #pragma unroll
    for (int i = 0; i < 2; ++i) g2l16(src + gB[i], (f16*)(dst + ldsoB[i]));
  };

  // fragment LDS byte offsets; phase k in {0,1} uses logical slots k*4+ks
  int offA[4][2], offB[4][2];
  #pragma unroll
  for (int i = 0; i < 4; ++i) {
    int rowA = wm*64 + i*16 + lr;
    int rowB = wn*64 + i*16 + lr;
    #pragma unroll
    for (int k = 0; k < 2; ++k) {
      offA[i][k] = rowA*128 + (((k*4 + ks) ^ (rowA & 7)) << 4);
      offB[i][k] = rowB*128 + (((k*4 + ks) ^ (rowB & 7)) << 4);
    }
  }

  f32x4 acc[4][4];
  #pragma unroll
  for (int i = 0; i < 4; ++i)
    #pragma unroll
    for (int j = 0; j < 4; ++j) acc[i][j] = f32x4{0.f, 0.f, 0.f, 0.f};

  const int nk = K >> 6;
  stageA(0); stageB(0); stageA(1); stageB(1);    // 12 loads/wave

  for (int t = 0; t < nk; ++t) {
    if (t + 2 < nk) stageA(t + 2);
    // queue after issue: [A(t+1):4, B(t+1):2, A(t+2):4] = 10 newest
    if (t + 2 < nk)      { asm volatile("s_waitcnt vmcnt(10)" ::: "memory"); }
    else if (t + 1 < nk) { asm volatile("s_waitcnt vmcnt(6)"  ::: "memory"); }
    else                 { asm volatile("s_waitcnt vmcnt(0)"  ::: "memory"); }
    __builtin_amdgcn_s_barrier();

    const char* pA = (const char*)smem + (t % 3)*49152;
    const char* pB = pA + 32768;

    // ---- phase 0: ks-half 0 ----
    f16x8 af0[4], bf0[4];
    #pragma unroll
    for (int i = 0; i < 4; ++i) {
      af0[i] = *(const f16x8*)(pA + offA[i][0]);
      bf0[i] = *(const f16x8*)(pB + offB[i][0]);
    }
    asm volatile("s_waitcnt lgkmcnt(0)" ::: "memory");
    __builtin_amdgcn_sched_barrier(0);
    __builtin_amdgcn_s_setprio(1);
    #pragma unroll
    for (int mi = 0; mi < 4; ++mi)
      #pragma unroll
      for (int ni = 0; ni < 4; ++ni)
        acc[mi][ni] = __builtin_amdgcn_mfma_f32_16x16x32_f16(af0[mi], bf0[ni], acc[mi][ni], 0, 0, 0);
    __builtin_amdgcn_s_setprio(0);
    __builtin_amdgcn_sched_barrier(0);
    __builtin_amdgcn_s_barrier();

    // ---- phase 1: ks-half 1 (+ mid-iter B prefetch) ----
    if (t + 2 < nk) stageB(t + 2);
    f16x8 af1[4], bf1[4];
    #pragma unroll
    for (int i = 0; i < 4; ++i) {
      af1[i] = *(const f16x8*)(pA + offA[i][1]);
      bf1[i] = *(const f16x8*)(pB + offB[i][1]);
    }
    asm volatile("s_waitcnt lgkmcnt(0)" ::: "memory");
    __builtin_amdgcn_sched_barrier(0);
    __builtin_amdgcn_s_setprio(1);
    #pragma unroll
    for (int mi = 0; mi < 4; ++mi)
      #pragma unroll
      for (int ni = 0; ni < 4; ++ni)
        acc[mi][ni] = __builtin_amdgcn_mfma_f32_16x16x32_f16(af1[mi], bf1[ni], acc[mi][ni], 0, 0, 0);
    __builtin_amdgcn_s_setprio(0);
    __builtin_amdgcn_sched_barrier(0);
    __builtin_amdgcn_s_barrier();              // all reads of tile t done
  }

  const int lq = lane >> 4;
  #pragma unroll
  for (int mi = 0; mi < 4; ++mi) {
    #pragma unroll
    for (int ni = 0; ni < 4; ++ni) {
      int col = n0 + wn*64 + ni*16 + lr;
      float bv = bias[col];
      int rbase = m0 + wm*64 + mi*16 + lq*4;
      #pragma unroll
      for (int r = 0; r < 4; ++r) {
        float val = acc[mi][ni][r] + bv;
        size_t o = (size_t)(rbase + r)*ldc + col;
        if (EPI == 0) {
          ((f16*)Cv)[o] = (f16)val;
        } else if (EPI == 1) {
          val = 0.5f * val * (1.f + erff(val * 0.70710678118654752f));
          ((f16*)Cv)[o] = (f16)val;
        } else {
          float* Cf = (float*)Cv;
          Cf[o] = Cf[o] + val;
        }
      }
    }
  }
}

// ---------------- score v3: diagonal-accumulated, D-quartered, 2 blocks/CU --
__device__ __forceinline__ void diag_epilogue2(float* ctile, f32x4 (&acc)[4][4],
                                               int dg, int b, float* __restrict__ score)
{
  const int tid = threadIdx.x;
  const int w = tid >> 6, lane = tid & 63;
  const int wm = w >> 1, wn = w & 1, lr = lane & 15, lq = lane >> 4;
  float total = 0.f;
  #pragma unroll
  for (int pass = 0; pass < 2; ++pass) {
    __builtin_amdgcn_s_barrier();                 // ctile free
    if (wn == pass) {
      #pragma unroll
      for (int mi = 0; mi < 4; ++mi) {
        #pragma unroll
        for (int ni = 0; ni < 4; ++ni) {
          int colL = ni*16 + lr;
          int row0 = wm*64 + mi*16 + lq*4;
          *(f32x4*)(&ctile[colL*128 + row0]) = acc[mi][ni];
        }
      }
    }
    asm volatile("s_waitcnt lgkmcnt(0)" ::: "memory");
    __builtin_amdgcn_s_barrier();
    if (tid < 255) {
      int delta = tid - 127;
      #pragma unroll 8
      for (int cc = 0; cc < 64; ++cc) {
        int r = pass*64 + cc + delta;
        if ((unsigned)r < 128u) total += ctile[cc*128 + r];
      }
    }
    asm volatile("s_waitcnt lgkmcnt(0)" ::: "memory");
  }
  __builtin_amdgcn_s_barrier();
  if (tid < 255) {
    int tau = dg*128 + (tid - 127);
    if (tau >= 1 && tau < T_) atomicAdd(&score[(size_t)b*T_ + tau], total);
  }
}

__global__ __launch_bounds__(256, 2) void score2_kernel(
    const f16* __restrict__ qkv, float* __restrict__ score)
{
  __shared__ __align__(16) f16 stage[3*8192];
  __shared__ float ctile[64*128];

  const int b = blockIdx.x, h = blockIdx.y, g = blockIdx.z;
  const int tid = threadIdx.x;
  const int w = tid >> 6, lane = tid & 63;

  const int o0 = (w*2+0)*1024 + lane*16;
  const int o1 = (w*2+1)*1024 + lane*16;
  const int r0 = o0 >> 6, r1 = o1 >> 6;
  const int s0 = ((o0>>4)&3) ^ ((r0>>1)&3);
  const int s1 = ((o1>>4)&3) ^ ((r1>>1)&3);
  const size_t goff0 = (size_t)r0*1536 + s0*8;
  const size_t goff1 = (size_t)r1*1536 + s1*8;
  const int l0 = (w*2+0)*512, l1 = (w*2+1)*512;

  const int nA = 16 - g;
  const int nsteps = 17*4;
  const int groupA_end = nA*4;

  const int wm = w >> 1, wn = w & 1;
  const int lr = lane & 15, ks = lane >> 4;
  int offQ[4], offK[4];
  #pragma unroll
  for (int i = 0; i < 4; ++i) {
    int row = wm*64 + i*16 + lr;
    offQ[i] = row*64 + ((ks ^ ((row>>1)&3)) << 4);
    int col = wn*64 + i*16 + lr;
    offK[i] = col*64 + ((ks ^ ((col>>1)&3)) << 4);
  }

  auto issue = [&](int sp) {
    int p = sp >> 2, kt = sp & 3;
    int ti, tj;
    if (p < nA) { tj = p; ti = p + g; }
    else        { tj = p - nA; ti = tj + 15 - g; }
    size_t qb = ((size_t)(b*T_ + ti*128))*1536 + h*128 + kt*32;
    size_t kb = ((size_t)(b*T_ + tj*128))*1536 + 512 + h*128 + kt*32;
    f16* dst = stage + (sp % 3)*8192;
    g2l16(qkv + qb + goff0, dst + l0);
    g2l16(qkv + qb + goff1, dst + l1);
    g2l16(qkv + kb + goff0, dst + 4096 + l0);
    g2l16(qkv + kb + goff1, dst + 4096 + l1);
  };

  f32x4 acc[4][4];
  #pragma unroll
  for (int i = 0; i < 4; ++i)
    #pragma unroll
    for (int j = 0; j < 4; ++j) acc[i][j] = f32x4{0.f, 0.f, 0.f, 0.f};

  issue(0);
  issue(1);
  asm volatile("s_waitcnt vmcnt(4)" ::: "memory");
  __builtin_amdgcn_s_barrier();

  for (int sp = 0; sp < nsteps; ++sp) {
    const char* base = (const char*)stage + (sp % 3)*16384;
    f16x8 af[4], bf[4];
    #pragma unroll
    for (int i = 0; i < 4; ++i) {
      af[i] = *(const f16x8*)(base + offQ[i]);
      bf[i] = *(const f16x8*)(base + 8192 + offK[i]);
    }
    if (sp + 2 < nsteps) issue(sp + 2);
    asm volatile("s_waitcnt lgkmcnt(0)" ::: "memory");
    __builtin_amdgcn_sched_barrier(0);
    #pragma unroll
    for (int mi = 0; mi < 4; ++mi)
      #pragma unroll
      for (int ni = 0; ni < 4; ++ni)
        acc[mi][ni] = __builtin_amdgcn_mfma_f32_16x16x32_f16(af[mi], bf[ni], acc[mi][ni], 0, 0, 0);
    if (sp + 2 < nsteps) { asm volatile("s_waitcnt vmcnt(4)" ::: "memory"); }
    else                 { asm volatile("s_waitcnt vmcnt(0)" ::: "memory"); }
    __builtin_amdgcn_s_barrier();
    if (sp == groupA_end - 1) {
      diag_epilogue2(ctile, acc, g, b, score);
      #pragma unroll
      for (int i = 0; i < 4; ++i)
        #pragma unroll
        for (int j = 0; j < 4; ++j) acc[i][j] = f32x4{0.f, 0.f, 0.f, 0.f};
    }
  }
  diag_epilogue2(ctile, acc, 15 - g, b, score);
}

__global__ void topk_kernel(const float* __restrict__ score, int* __restrict__ lags)
{
  const int b = blockIdx.x, tid = threadIdx.x;
  __shared__ float vals[T_];
  __shared__ float rmax[256];
  __shared__ int   rarg[256];
  __shared__ int   outk[8];
  for (int t = tid; t < T_; t += 256) vals[t] = (t == 0) ? -1e30f : score[(size_t)b*T_ + t];
  __syncthreads();
  for (int k = 0; k < 8; ++k) {
    float m = -1e30f; int mi = 0x7fffffff;
    for (int t = tid; t < T_; t += 256) {
      float v = vals[t];
      if (v > m || (v == m && t < mi)) { m = v; mi = t; }
    }
    rmax[tid] = m; rarg[tid] = mi;
    __syncthreads();
    for (int s = 128; s > 0; s >>= 1) {
      if (tid < s) {
        float v2 = rmax[tid+s]; int i2 = rarg[tid+s];
        if (v2 > rmax[tid] || (v2 == rmax[tid] && i2 < rarg[tid])) { rmax[tid] = v2; rarg[tid] = i2; }
      }
      __syncthreads();
    }
    if (tid == 0) { outk[k] = rarg[0]; vals[rarg[0]] = -1e30f; }
    __syncthreads();
  }
  if (tid < 8) lags[b*8 + tid] = outk[tid];
}

// trend1 = movavg25(x) -> out_trend ; s1 = x - trend1 -> f16
__global__ void decomp1_kernel(const float* __restrict__ x,
                               float* __restrict__ trend1, f16* __restrict__ s16)
{
  int idx = blockIdx.x*256 + threadIdx.x;              // (b, t, d4)
  int d4 = idx & 127, t = (idx >> 7) & (T_-1), b = idx >> 18;
  const float* xb = x + ((size_t)b*T_)*D_ + d4*4;
  f32x4 sum = {0.f,0.f,0.f,0.f};
  f32x4 center = {0.f,0.f,0.f,0.f};
  #pragma unroll
  for (int j = -12; j <= 12; ++j) {
    int tt = t + j; tt = tt < 0 ? 0 : (tt > T_-1 ? T_-1 : tt);
    f32x4 v = *(const f32x4*)(xb + (size_t)tt*D_);
    sum += v;
    if (j == 0) center = v;
  }
  f32x4 tr = sum * (1.f/25.f);
  size_t o = ((size_t)(b*T_ + t))*D_ + d4*4;
  *(f32x4*)(trend1 + o) = tr;
  f32x4 s = center - tr;
  f16x4 hv;
  #pragma unroll
  for (int i = 0; i < 4; ++i) hv[i] = (f16)s[i];
  *(f16x4*)(s16 + o) = hv;
}

// sac16 (act0, f16): trend2 = movavg25 ; s2 = sac - trend2 -> seas(f32) + s2_16 ;
// trend_io += trend2
__global__ void decomp2_kernel(const f16* __restrict__ sac,
                               float* __restrict__ seas, float* __restrict__ trend_io,
                               f16* __restrict__ s2_16)
{
  int idx = blockIdx.x*256 + threadIdx.x;
  int d4 = idx & 127, t = (idx >> 7) & (T_-1), b = idx >> 18;
  const f16* sb = sac + ((size_t)b*T_)*D_ + d4*4;
  f32x4 sum = {0.f,0.f,0.f,0.f};
  f32x4 center = {0.f,0.f,0.f,0.f};
  #pragma unroll
  for (int j = -12; j <= 12; ++j) {
    int tt = t + j; tt = tt < 0 ? 0 : (tt > T_-1 ? T_-1 : tt);
    f16x4 v = *(const f16x4*)(sb + (size_t)tt*D_);
    f32x4 vf = { (float)v[0], (float)v[1], (float)v[2], (float)v[3] };
    sum += vf;
    if (j == 0) center = vf;
  }
  f32x4 tr = sum * (1.f/25.f);
  size_t o = ((size_t)(b*T_ + t))*D_ + d4*4;
  f32x4 s = center - tr;
  *(f32x4*)(seas + o) = s;
  f16x4 hv;
  #pragma unroll
  for (int i = 0; i < 4; ++i) hv[i] = (f16)s[i];
  *(f16x4*)(s2_16 + o) = hv;
  f32x4 told = *(const f32x4*)(trend_io + o);
  *(f32x4*)(trend_io + o) = told + tr;
}

// act0 := s1_16 + (1/8) sum_k v[(t - lag_k) mod T]   (in-place, element-wise)
__global__ void gather_kernel(const f16* __restrict__ qkv, f16* __restrict__ act,
                              const int* __restrict__ lags)
{
  int idx = blockIdx.x*256 + threadIdx.x;              // (b, t, d8)
  int d8 = idx & 63, t = (idx >> 6) & (T_-1), b = idx >> 17;
  const f16* vb = qkv + (size_t)b*T_*1536 + 1024 + d8*8;
  f16* ap = act + ((size_t)(b*T_ + t))*D_ + d8*8;
  f16x8 s = *(const f16x8*)ap;
  float a[8];
  #pragma unroll
  for (int j = 0; j < 8; ++j) a[j] = (float)s[j];
  #pragma unroll
  for (int k = 0; k < 8; ++k) {
    int lag = lags[b*8 + k];
    int tt = (t - lag + T_) & (T_-1);
    f16x8 v = *(const f16x8*)(vb + (size_t)tt*1536);
    #pragma unroll
    for (int j = 0; j < 8; ++j) a[j] += 0.125f * (float)v[j];
  }
  f16x8 o;
  #pragma unroll
  for (int j = 0; j < 8; ++j) o[j] = (f16)a[j];
  *(f16x8*)ap = o;
}

// convert weights to f16, transposed to (N x K) row-major; concat qkv biases
__global__ void prepack_kernel(const float* __restrict__ Wq, const float* __restrict__ Wk,
                               const float* __restrict__ Wv, const float* __restrict__ bq,
                               const float* __restrict__ bk, const float* __restrict__ bv,
                               const float* __restrict__ W1, const float* __restrict__ W2,
                               f16* __restrict__ wcat, f16* __restrict__ w1t,
                               f16* __restrict__ w2t, float* __restrict__ bcat)
{
  int i = blockIdx.x*256 + threadIdx.x;
  if (i < 786432) {                       // wcat: 1536 x 512
    int n = i >> 9, k = i & 511;
    int sel = n >> 9, nn = n & 511;
    const float* W = sel == 0 ? Wq : (sel == 1 ? Wk : Wv);
    wcat[i] = (f16)W[k*512 + nn];
  } else if (i < 1835008) {               // w1t: 2048 x 512
    int j = i - 786432;
    int n = j >> 9, k = j & 511;
    w1t[j] = (f16)W1[k*2048 + n];
  } else if (i < 2883584) {               // w2t: 512 x 2048
    int j = i - 1835008;
    int n = j >> 11, k = j & 2047;
    w2t[j] = (f16)W2[k*512 + n];
  } else if (i < 2885120) {               // bcat: 1536
    int j = i - 2883584;
    bcat[j] = j < 512 ? bq[j] : (j < 1024 ? bk[j-512] : bv[j-1024]);
  }
}

extern "C" void kernel_launch(void* const* d_in, const int* in_sizes, int n_in,
                              void* d_out, int out_size, void* d_ws, size_t ws_size,
                              hipStream_t stream)
{
  const float* x  = (const float*)d_in[0];
  const float* Wq = (const float*)d_in[1];
  const float* bq = (const float*)d_in[2];
  const float* Wk = (const float*)d_in[3];
  const float* bk = (const float*)d_in[4];
  const float* Wv = (const float*)d_in[5];
  const float* bv = (const float*)d_in[6];
  const float* W1 = (const float*)d_in[7];
  const float* b1 = (const float*)d_in[8];
  const float* W2 = (const float*)d_in[9];
  const float* b2 = (const float*)d_in[10];

  float* out_seas  = (float*)d_out;
  float* out_trend = out_seas + (size_t)NB*T_*D_;

  char* ws = (char*)d_ws;
  f16*   act0  = (f16*)(ws);                        //  [0, 32MiB): s1 -> sac (in place)
  f16*   qkv   = (f16*)(ws + 33554432ull);          //  [32, 128MiB): [q|k|v]
  f16*   s2_16 = qkv;                               //  [32, 64MiB) after qkv dead
  f16*   h16   = (f16*)(ws + 67108864ull);          //  [64, 192MiB): FFN hidden full-M
  f16*   wcat  = (f16*)(ws + 201326592ull);
  f16*   w1t   = (f16*)(ws + 202899456ull);
  f16*   w2t   = (f16*)(ws + 204996608ull);
  float* bcat  = (float*)(ws + 207093760ull);
  float* score = (float*)(ws + 207099904ull);
  int*   lags  = (int*)(ws + 207230976ull);

  (void)hipMemsetAsync(score, 0, (size_t)NB*T_*sizeof(float), stream);
  prepack_kernel<<<11270, 256, 0, stream>>>(Wq, Wk, Wv, bq, bk, bv, W1, W2,
                                            wcat, w1t, w2t, bcat);
  decomp1_kernel<<<NB*T_*(D_/4)/256, 256, 0, stream>>>(x, out_trend, act0);
  // QKV: (32768 x 512) @ (512 x 1536) -> qkv f16   [128 m x 12 n = 1536 blocks]
  gemm_kernel<0><<<1536, 512, 0, stream>>>(act0, 512, wcat, 512, qkv, 1536, bcat, 512, 12);
  score2_kernel<<<dim3(16, 4, 8), 256, 0, stream>>>(qkv, score);
  topk_kernel<<<NB, 256, 0, stream>>>(score, lags);
  gather_kernel<<<NB*T_*(D_/8)/256, 256, 0, stream>>>(qkv, act0, lags);
  decomp2_kernel<<<NB*T_*(D_/4)/256, 256, 0, stream>>>(act0, out_seas, out_trend, s2_16);
  // FFN full-M: (32768x512)@(512x2048) -> h16 ; (32768x2048)@(2048x512) += seas
  gemm_kernel<1><<<128*16, 512, 0, stream>>>(s2_16, 512, w1t, 512, h16, 2048, b1, 512, 16);
  gemm_kernel<2><<<128*4, 512, 0, stream>>>(h16, 2048, w2t, 2048, out_seas, 512, b2, 2048, 4);
}